// Round 1
// baseline (166.409 us; speedup 1.0000x reference)
//
#include <hip/hip_runtime.h>
#include <math.h>

typedef __attribute__((ext_vector_type(8))) short short8;
typedef __attribute__((ext_vector_type(4))) float f32x4;
typedef unsigned short ushort_t;

#define TSEQ   4096
#define NBATCH 4
#define DMODEL 768
#define HS     64
#define KSPLIT 4

static __device__ __forceinline__ ushort_t f2bf(float f) {
  union { float f; unsigned u; } v; v.f = f;
  unsigned r = v.u + 0x7fffu + ((v.u >> 16) & 1u);   // RNE
  return (ushort_t)(r >> 16);
}
static __device__ __forceinline__ float bf2f(ushort_t u) {
  union { unsigned u; float f; } v; v.u = ((unsigned)u) << 16; return v.f;
}

#define MFMA16(a,b,c) __builtin_amdgcn_mfma_f32_16x16x32_bf16((a),(b),(c),0,0,0)

// ---------------- W prep (coalesced LDS transpose) ----------------
// grid 36 = 3 mats x 12 k-chunks of 64.  Wt[n'=m*64+n][k] bf16.
__global__ __launch_bounds__(256) void wprep(
    const float* __restrict__ Wq, const float* __restrict__ Wk,
    const float* __restrict__ Wv, ushort_t* __restrict__ Wt)
{
  __shared__ float lds[64 * 65];
  const int m = blockIdx.x / 12, kc = blockIdx.x % 12, k0 = kc * 64;
  const float* W = (m == 0) ? Wq : (m == 1) ? Wk : Wv;
  const int tid = threadIdx.x;
#pragma unroll
  for (int i = 0; i < 16; i++) {
    const int row = i * 4 + (tid >> 6), col = tid & 63;
    lds[row * 65 + col] = W[(size_t)(k0 + row) * HS + col];   // coalesced
  }
  __syncthreads();
#pragma unroll
  for (int i = 0; i < 16; i++) {
    const int n = i * 4 + (tid >> 6), kk = tid & 63;
    Wt[(size_t)(m * 64 + n) * DMODEL + k0 + kk] = f2bf(lds[kk * 65 + n]);
  }
}

// ---------------- QKV projection: barrier-free per-wave GEMM ----------------
// Round-6 restructure: the old 32-row/512-block version was convoy-bound
// (2 blocks/CU, per-K-step __syncthreads draining vmcnt; MfmaUtil 3.7%,
// HBM 9.3%, occupancy 15.9%).  Now: block = 16 rows, 4 waves, each wave
// owns 48 cols (3 n-tiles) and loads its A-fragments DIRECTLY from x
// (16B-aligned float4 per lane, L1 catches the 4x intra-block reuse),
// converting fp32->bf16 in-register.  No LDS, no barriers in the main
// loop; 1024 blocks -> 4 blocks/CU, 16 waves/CU, all free-running.
// LDS + 1 barrier only in the v-transpose epilogue.
__global__ __launch_bounds__(256, 4) void qkv_mfma(
    const float* __restrict__ x, const ushort_t* __restrict__ Wt,
    ushort_t* __restrict__ q, ushort_t* __restrict__ kO, ushort_t* __restrict__ vT)
{
  __shared__ __align__(16) float vls[16 * 65];   // epilogue only, 4.2 KB

  const int tid  = threadIdx.x;
  const int ns   = tid >> 6;                     // wave id = column split 0..3
  const int lane = tid & 63;
  const int l16  = lane & 15, quad = lane >> 4;
  const int M0   = blockIdx.x * 16;

  // A-frag source: lane (l16,quad) holds row l16, k-bytes quad*8..+7
  const float*    xr = x  + (size_t)(M0 + l16) * DMODEL + quad * 8;
  // B-frag source: col = ns*48 + nt*16 + l16, k-offset quad*8
  const ushort_t* wb = Wt + (size_t)(ns * 48 + l16) * DMODEL + quad * 8;

  f32x4 acc[3];
#pragma unroll
  for (int nt = 0; nt < 3; nt++) acc[nt] = (f32x4){0.f, 0.f, 0.f, 0.f};

  // 1-deep register prefetch (ks = 0)
  float4 xp0 = *(const float4*)(xr);
  float4 xp1 = *(const float4*)(xr + 4);
  float4 xp2 = *(const float4*)(xr + 32);
  float4 xp3 = *(const float4*)(xr + 36);
  short8 bp[6];
#pragma unroll
  for (int nt = 0; nt < 3; nt++)
#pragma unroll
    for (int kc = 0; kc < 2; kc++)
      bp[nt * 2 + kc] = *(const short8*)(wb + (size_t)nt * 16 * DMODEL + kc * 32);

  for (int ks = 0; ks < DMODEL / 64; ks++) {
    const float4 xc0 = xp0, xc1 = xp1, xc2 = xp2, xc3 = xp3;
    short8 bc[6];
#pragma unroll
    for (int t = 0; t < 6; t++) bc[t] = bp[t];
    if (ks < DMODEL / 64 - 1) {                  // prefetch next K-step
      const float* xn = xr + (ks + 1) * 64;
      xp0 = *(const float4*)(xn);
      xp1 = *(const float4*)(xn + 4);
      xp2 = *(const float4*)(xn + 32);
      xp3 = *(const float4*)(xn + 36);
#pragma unroll
      for (int nt = 0; nt < 3; nt++)
#pragma unroll
        for (int kc = 0; kc < 2; kc++)
          bp[nt * 2 + kc] =
              *(const short8*)(wb + (size_t)nt * 16 * DMODEL + (ks + 1) * 64 + kc * 32);
    }
    // in-register fp32->bf16 A-fragments (k-chunks kc=0 and kc=1)
    short8 a0, a1;
    a0[0] = f2bf(xc0.x); a0[1] = f2bf(xc0.y); a0[2] = f2bf(xc0.z); a0[3] = f2bf(xc0.w);
    a0[4] = f2bf(xc1.x); a0[5] = f2bf(xc1.y); a0[6] = f2bf(xc1.z); a0[7] = f2bf(xc1.w);
    a1[0] = f2bf(xc2.x); a1[1] = f2bf(xc2.y); a1[2] = f2bf(xc2.z); a1[3] = f2bf(xc2.w);
    a1[4] = f2bf(xc3.x); a1[5] = f2bf(xc3.y); a1[6] = f2bf(xc3.z); a1[7] = f2bf(xc3.w);
#pragma unroll
    for (int nt = 0; nt < 3; nt++) {
      acc[nt] = MFMA16(a0, bc[nt * 2 + 0], acc[nt]);
      acc[nt] = MFMA16(a1, bc[nt * 2 + 1], acc[nt]);
    }
  }

  // ---- epilogue: q/k direct; v via LDS transpose ----
#pragma unroll
  for (int nt = 0; nt < 3; nt++) {
    const int gnt = ns * 3 + nt;                 // 0..11
    const int mat = gnt >> 2;                    // 0=q 1=k 2=v (wave-uniform)
    const int col = (gnt & 3) * 16 + l16;
    if (mat == 0) {
#pragma unroll
      for (int r = 0; r < 4; r++)
        q[(size_t)(M0 + quad * 4 + r) * HS + col] = f2bf(acc[nt][r] * 0.125f);
    } else if (mat == 1) {
#pragma unroll
      for (int r = 0; r < 4; r++)
        kO[(size_t)(M0 + quad * 4 + r) * HS + col] = f2bf(acc[nt][r]);
    } else {
#pragma unroll
      for (int r = 0; r < 4; r++)
        vls[(quad * 4 + r) * 65 + col] = acc[nt][r];
    }
  }
  __syncthreads();
  if (tid < 128) {                               // 64 dims x 2 segs of 8 t
    const int d = tid >> 1, seg = tid & 1;
    short8 pk;
#pragma unroll
    for (int i = 0; i < 8; i++) pk[i] = (short)f2bf(vls[(seg * 8 + i) * 65 + d]);
    *(short8*)(vT + ((size_t)(M0 >> 12) * HS + d) * TSEQ + (M0 & (TSEQ - 1)) + seg * 8) = pk;
  }
}

// ---------------- attention pass 1: partial flash attention ----------------
// grid = 128 jt (descending) x B x KSPLIT(4) = 2048 blocks, 128 thr (2 waves).
// Block: 32 q-rows (wave w: 16), 64-key chunks with kt%4==s, shared LDS K/V
// (pitch 72), register-prefetched. Partials (m,l,O) -> ws.
#define KP 72
__global__ __launch_bounds__(128) void attn_part(
    const ushort_t* __restrict__ q, const ushort_t* __restrict__ k,
    const ushort_t* __restrict__ vT, float* __restrict__ ML, ushort_t* __restrict__ OP)
{
  __shared__ __align__(16) ushort_t sK[64 * KP];     // [key][d]
  __shared__ __align__(16) ushort_t sV[64 * KP];     // [d][key]
  __shared__ __align__(16) ushort_t sP[2][16 * KP];  // per-wave P

  const int idx  = blockIdx.x;
  const int s    = idx & 3;
  const int b    = (idx >> 2) & 3;
  const int jt   = 127 - (idx >> 4);           // descending work order
  const int tid  = threadIdx.x;
  const int w    = tid >> 6;
  const int lane = tid & 63;
  const int l16  = lane & 15, quad = lane >> 4;
  const int R0   = jt * 32 + w * 16;

  const ushort_t* qg = q  + (size_t)b * TSEQ * HS;
  const ushort_t* kg = k  + (size_t)b * TSEQ * HS;
  const ushort_t* vg = vT + (size_t)b * HS * TSEQ;

  // Q B-operand frags (q pre-scaled 1/8): B[k=d][n=qrow]
  const short8 qf0 = *(const short8*)(qg + (R0 + l16) * HS +      quad * 8);
  const short8 qf1 = *(const short8*)(qg + (R0 + l16) * HS + 32 + quad * 8);

  f32x4 o[4];
#pragma unroll
  for (int dt = 0; dt < 4; dt++) o[dt] = (f32x4){0.f, 0.f, 0.f, 0.f};
  float mrow = -INFINITY, lrow = 0.f;          // per-lane qrow = R0 + l16

  const int nkt = jt / 2 + 1;                  // 64-key chunks incl. diagonal
  short8 kpre[4], vpre[4];
  int kt = s;
  if (kt < nkt) {
    const int k0 = kt * 64;
#pragma unroll
    for (int i = 0; i < 4; i++) {
      const int c = i * 128 + tid, key = c >> 3, ch = c & 7;
      kpre[i] = *(const short8*)(kg + (size_t)(k0 + key) * HS + ch * 8);
      vpre[i] = *(const short8*)(vg + (size_t)key * TSEQ + k0 + ch * 8);
    }
  }
  for (; kt < nkt; kt += KSPLIT) {
    const int k0 = kt * 64;
    __syncthreads();                           // prior iter's LDS reads done
#pragma unroll
    for (int i = 0; i < 4; i++) {
      const int c = i * 128 + tid, key = c >> 3, ch = c & 7;
      *(short8*)(sK + key * KP + ch * 8) = kpre[i];
      *(short8*)(sV + key * KP + ch * 8) = vpre[i];
    }
    if (kt + KSPLIT < nkt) {                   // prefetch next chunk
      const int kn = (kt + KSPLIT) * 64;
#pragma unroll
      for (int i = 0; i < 4; i++) {
        const int c = i * 128 + tid, key = c >> 3, ch = c & 7;
        kpre[i] = *(const short8*)(kg + (size_t)(kn + key) * HS + ch * 8);
        vpre[i] = *(const short8*)(vg + (size_t)key * TSEQ + kn + ch * 8);
      }
    }
    __syncthreads();                           // staged tile visible
    // ---- S^T = K Q^T : C[key = ct*16+quad*4+r][qrow = l16] ----
    f32x4 sT[4];
#pragma unroll
    for (int ct = 0; ct < 4; ct++) {
      sT[ct] = (f32x4){0.f, 0.f, 0.f, 0.f};
      const short8 kfa = *(const short8*)(sK + (ct * 16 + l16) * KP +      quad * 8);
      const short8 kfb = *(const short8*)(sK + (ct * 16 + l16) * KP + 32 + quad * 8);
      sT[ct] = MFMA16(kfa, qf0, sT[ct]);
      sT[ct] = MFMA16(kfb, qf1, sT[ct]);
    }
    if (k0 + 63 > R0) {                        // causal mask, diagonal only
      const int qrow = R0 + l16;
#pragma unroll
      for (int ct = 0; ct < 4; ct++)
#pragma unroll
        for (int r = 0; r < 4; r++)
          sT[ct][r] = (k0 + ct * 16 + quad * 4 + r <= qrow) ? sT[ct][r] : -INFINITY;
    }
    // ---- online softmax (per-lane row; 2 cross-quad shuffles) ----
    float tm = -INFINITY;
#pragma unroll
    for (int ct = 0; ct < 4; ct++)
#pragma unroll
      for (int r = 0; r < 4; r++) tm = fmaxf(tm, sT[ct][r]);
    tm = fmaxf(tm, __shfl_xor(tm, 16));
    tm = fmaxf(tm, __shfl_xor(tm, 32));
    const float mn = fmaxf(mrow, tm);
    const float al = __expf(mrow - mn);
    mrow = mn;
    float ps = 0.f;
#pragma unroll
    for (int ct = 0; ct < 4; ct++)
#pragma unroll
      for (int r = 0; r < 4; r++) { sT[ct][r] = __expf(sT[ct][r] - mn); ps += sT[ct][r]; }
    ps += __shfl_xor(ps, 16);
    ps += __shfl_xor(ps, 32);
    lrow = lrow * al + ps;
    // ---- P -> LDS (A-layout), O rescale, PV ----
    ushort_t* Pw = &sP[w][0];
#pragma unroll
    for (int ct = 0; ct < 4; ct++) {
      ushort4 pk;
      pk.x = f2bf(sT[ct][0]); pk.y = f2bf(sT[ct][1]);
      pk.z = f2bf(sT[ct][2]); pk.w = f2bf(sT[ct][3]);
      *(ushort4*)(Pw + l16 * KP + ct * 16 + quad * 4) = pk;
    }
    float alo[4];
#pragma unroll
    for (int r = 0; r < 4; r++) alo[r] = __shfl(al, quad * 4 + r);
#pragma unroll
    for (int dt = 0; dt < 4; dt++)
#pragma unroll
      for (int r = 0; r < 4; r++) o[dt][r] *= alo[r];
    const short8 pf0 = *(const short8*)(Pw + l16 * KP +      quad * 8);
    const short8 pf1 = *(const short8*)(Pw + l16 * KP + 32 + quad * 8);
#pragma unroll
    for (int dt = 0; dt < 4; dt++) {
      const short8 vfa = *(const short8*)(sV + (dt * 16 + l16) * KP +      quad * 8);
      const short8 vfb = *(const short8*)(sV + (dt * 16 + l16) * KP + 32 + quad * 8);
      o[dt] = MFMA16(pf0, vfa, o[dt]);
      o[dt] = MFMA16(pf1, vfb, o[dt]);
    }
  }

  // ---- write partials: ML fp32 [B][KSPLIT][T][2], OP bf16 [B][KSPLIT][T][64] ----
  const size_t base = ((size_t)(b * KSPLIT + s) * TSEQ);
  if (quad == 0) {
    ML[(base + R0 + l16) * 2 + 0] = mrow;
    ML[(base + R0 + l16) * 2 + 1] = lrow;
  }
#pragma unroll
  for (int dt = 0; dt < 4; dt++)
#pragma unroll
    for (int r = 0; r < 4; r++)
      OP[(base + R0 + quad * 4 + r) * HS + dt * 16 + l16] = f2bf(o[dt][r]);
}

// ---------------- attention pass 2: merge the KSPLIT partials ----------------
// grid 1024 x 256: block = 16 rows x 16 dim-groups.
__global__ __launch_bounds__(256) void attn_merge(
    const float* __restrict__ ML, const ushort_t* __restrict__ OP,
    float* __restrict__ out)
{
  const int row = blockIdx.x * 16 + (threadIdx.x >> 4);   // 0..16383
  const int b   = row >> 12, t = row & (TSEQ - 1);
  const int d0  = (threadIdx.x & 15) * 4;
  float m[KSPLIT], l[KSPLIT];
  float M = -INFINITY;
#pragma unroll
  for (int ss = 0; ss < KSPLIT; ss++) {
    const size_t i = ((size_t)(b * KSPLIT + ss) * TSEQ + t);
    m[ss] = ML[i * 2]; l[ss] = ML[i * 2 + 1];
    M = fmaxf(M, m[ss]);
  }
  float den = 0.f;
  float4 num = make_float4(0.f, 0.f, 0.f, 0.f);
#pragma unroll
  for (int ss = 0; ss < KSPLIT; ss++) {
    const float a = __expf(m[ss] - M);          // zero-trip split: weight 0
    den += l[ss] * a;
    const size_t i = ((size_t)(b * KSPLIT + ss) * TSEQ + t);
    const ushort4 u = *(const ushort4*)(OP + i * HS + d0);
    num.x += a * bf2f(u.x); num.y += a * bf2f(u.y);
    num.z += a * bf2f(u.z); num.w += a * bf2f(u.w);
  }
  const float inv = 1.f / den;
  *(float4*)(out + (size_t)row * HS + d0) =
      make_float4(num.x * inv, num.y * inv, num.z * inv, num.w * inv);
}

extern "C" void kernel_launch(void* const* d_in, const int* in_sizes, int n_in,
                              void* d_out, int out_size, void* d_ws, size_t ws_size,
                              hipStream_t stream) {
  const float* x  = (const float*)d_in[0];
  const float* Wq = (const float*)d_in[1];
  const float* Wk = (const float*)d_in[2];
  const float* Wv = (const float*)d_in[3];
  float* out = (float*)d_out;

  // ws: Wt 288K | q 2M | k 2M | vT 2M | ML 512K | OP 8M   (total ~15 MB)
  char* ws = (char*)d_ws;
  ushort_t* Wt = (ushort_t*)ws;
  ushort_t* qb = (ushort_t*)(ws + 294912);
  ushort_t* kb = (ushort_t*)(ws + 294912 + 2097152);
  ushort_t* vb = (ushort_t*)(ws + 294912 + 2 * 2097152);
  float*    ml = (float*)   (ws + 294912 + 3 * 2097152);
  ushort_t* op = (ushort_t*)(ws + 294912 + 3 * 2097152 + 524288);

  wprep<<<36, 256, 0, stream>>>(Wq, Wk, Wv, Wt);
  qkv_mfma<<<(NBATCH * TSEQ) / 16, 256, 0, stream>>>(x, Wt, qb, kb, vb);
  attn_part<<<128 * NBATCH * KSPLIT, 128, 0, stream>>>(qb, kb, vb, ml, op);
  attn_merge<<<1024, 256, 0, stream>>>(ml, op, out);
}

// Round 4
// 151.926 us; speedup vs baseline: 1.0953x; 1.0953x over previous
//
#include <hip/hip_runtime.h>
#include <math.h>

typedef __attribute__((ext_vector_type(8))) short short8;
typedef __attribute__((ext_vector_type(4))) float f32x4;
typedef unsigned short ushort_t;

#define TSEQ   4096
#define NBATCH 4
#define DMODEL 768
#define HS     64
#define KSPLIT 4

static __device__ __forceinline__ ushort_t f2bf(float f) {
  union { float f; unsigned u; } v; v.f = f;
  unsigned r = v.u + 0x7fffu + ((v.u >> 16) & 1u);   // RNE
  return (ushort_t)(r >> 16);
}
static __device__ __forceinline__ float bf2f(ushort_t u) {
  union { unsigned u; float f; } v; v.u = ((unsigned)u) << 16; return v.f;
}

#define MFMA16(a,b,c) __builtin_amdgcn_mfma_f32_16x16x32_bf16((a),(b),(c),0,0,0)

// ---------------- W prep (coalesced LDS transpose) ----------------
// grid 36 = 3 mats x 12 k-chunks of 64.  Wt[n'=m*64+n][k] bf16.
__global__ __launch_bounds__(256) void wprep(
    const float* __restrict__ Wq, const float* __restrict__ Wk,
    const float* __restrict__ Wv, ushort_t* __restrict__ Wt)
{
  __shared__ float lds[64 * 65];
  const int m = blockIdx.x / 12, kc = blockIdx.x % 12, k0 = kc * 64;
  const float* W = (m == 0) ? Wq : (m == 1) ? Wk : Wv;
  const int tid = threadIdx.x;
#pragma unroll
  for (int i = 0; i < 16; i++) {
    const int row = i * 4 + (tid >> 6), col = tid & 63;
    lds[row * 65 + col] = W[(size_t)(k0 + row) * HS + col];   // coalesced
  }
  __syncthreads();
#pragma unroll
  for (int i = 0; i < 16; i++) {
    const int n = i * 4 + (tid >> 6), kk = tid & 63;
    Wt[(size_t)(m * 64 + n) * DMODEL + k0 + kk] = f2bf(lds[kk * 65 + n]);
  }
}

// ---------------- QKV projection: async-LDS-staged per-block GEMM ----------
// Round-8 (= round-7 minus inline asm): round-6's register prefetch was
// collapsed by the allocator (VGPR_Count=36 -> loads sunk to use, bare
// 900-cy chains, 62 us).  Structural fix: stage the block's ENTIRE x panel
// (16 rows x 768 fp32, 49.4 KB, pitch 772 for bank spread) via
// global_load_lds width=16 -- 12 async issues per wave, all in flight,
// drained by ONE __syncthreads.  The 12-step K-loop then runs from LDS only
// (ds_read_b128 + scalar RNE convert), B-frags 1-deep L2-hot register
// prefetch.  3 blocks/CU (LDS-limited), 12 waves/CU.
#define XPITCH 772
__global__ __launch_bounds__(256, 3) void qkv_mfma(
    const float* __restrict__ x, const ushort_t* __restrict__ Wt,
    ushort_t* __restrict__ q, ushort_t* __restrict__ kO, ushort_t* __restrict__ vT)
{
  __shared__ __align__(16) float xp[16 * XPITCH];   // 49.4 KB

  const int tid  = threadIdx.x;
  const int ns   = tid >> 6;                     // wave id = column split 0..3
  const int lane = tid & 63;
  const int l16  = lane & 15, quad = lane >> 4;
  const int M0   = blockIdx.x * 16;

  // ---- async stage: wave ns loads rows ns*4..ns*4+3, 3 x 1KB chunks each
  {
    const int row0 = ns * 4;
#pragma unroll
    for (int r = 0; r < 4; r++) {
      const float* gsrc = x + (size_t)(M0 + row0 + r) * DMODEL;
      float*       ldst = xp + (row0 + r) * XPITCH;
#pragma unroll
      for (int c = 0; c < 3; c++) {
        __builtin_amdgcn_global_load_lds(
            (const __attribute__((address_space(1))) float*)(gsrc + c * 256 + lane * 4),
            (__attribute__((address_space(3))) float*)(ldst + c * 256),
            16, 0, 0);
      }
    }
  }

  // B-frag pointers: col = ns*48 + nt*16 + l16, k-offset quad*8
  const ushort_t* wb = Wt + (size_t)(ns * 48 + l16) * DMODEL + quad * 8;
  short8 bp[6];
#pragma unroll
  for (int nt = 0; nt < 3; nt++)
#pragma unroll
    for (int kc = 0; kc < 2; kc++)
      bp[nt * 2 + kc] = *(const short8*)(wb + (size_t)nt * 16 * DMODEL + kc * 32);

  f32x4 acc[3];
#pragma unroll
  for (int nt = 0; nt < 3; nt++) acc[nt] = (f32x4){0.f, 0.f, 0.f, 0.f};

  __syncthreads();                               // drains staging (vmcnt 0)

  for (int ks = 0; ks < DMODEL / 64; ks++) {
    short8 bc[6];
#pragma unroll
    for (int t = 0; t < 6; t++) bc[t] = bp[t];
    if (ks < DMODEL / 64 - 1) {                  // L2-hot B prefetch
#pragma unroll
      for (int nt = 0; nt < 3; nt++)
#pragma unroll
        for (int kc = 0; kc < 2; kc++)
          bp[nt * 2 + kc] =
              *(const short8*)(wb + (size_t)nt * 16 * DMODEL + (ks + 1) * 64 + kc * 32);
    }
#pragma unroll
    for (int kc = 0; kc < 2; kc++) {
      const float* ar = xp + l16 * XPITCH + ks * 64 + kc * 32 + quad * 8;
      const float4 f0 = *(const float4*)(ar);
      const float4 f1 = *(const float4*)(ar + 4);
      short8 af;
      af[0] = f2bf(f0.x); af[1] = f2bf(f0.y); af[2] = f2bf(f0.z); af[3] = f2bf(f0.w);
      af[4] = f2bf(f1.x); af[5] = f2bf(f1.y); af[6] = f2bf(f1.z); af[7] = f2bf(f1.w);
#pragma unroll
      for (int nt = 0; nt < 3; nt++)
        acc[nt] = MFMA16(af, bc[nt * 2 + kc], acc[nt]);
    }
  }

  // ---- epilogue: q/k direct; v via LDS transpose (panel reused as vls) ----
#pragma unroll
  for (int nt = 0; nt < 3; nt++) {
    const int gnt = ns * 3 + nt;                 // 0..11
    const int mat = gnt >> 2;                    // 0=q 1=k 2=v (wave-uniform)
    const int col = (gnt & 3) * 16 + l16;
    if (mat == 0) {
#pragma unroll
      for (int r = 0; r < 4; r++)
        q[(size_t)(M0 + quad * 4 + r) * HS + col] = f2bf(acc[nt][r] * 0.125f);
    } else if (mat == 1) {
#pragma unroll
      for (int r = 0; r < 4; r++)
        kO[(size_t)(M0 + quad * 4 + r) * HS + col] = f2bf(acc[nt][r]);
    }
  }
  __syncthreads();                               // all panel reads done
  float* vls = xp;                               // reuse as [16][65] fp32
#pragma unroll
  for (int nt = 0; nt < 3; nt++) {
    const int gnt = ns * 3 + nt;
    if ((gnt >> 2) == 2) {
      const int col = (gnt & 3) * 16 + l16;
#pragma unroll
      for (int r = 0; r < 4; r++)
        vls[(quad * 4 + r) * 65 + col] = acc[nt][r];
    }
  }
  __syncthreads();
  if (tid < 128) {                               // 64 dims x 2 segs of 8 t
    const int d = tid >> 1, seg = tid & 1;
    short8 pk;
#pragma unroll
    for (int i = 0; i < 8; i++) pk[i] = (short)f2bf(vls[(seg * 8 + i) * 65 + d]);
    *(short8*)(vT + ((size_t)(M0 >> 12) * HS + d) * TSEQ + (M0 & (TSEQ - 1)) + seg * 8) = pk;
  }
}

// ---------------- attention pass 1: partial flash attention ----------------
// grid = 128 jt (descending) x B x KSPLIT(4) = 2048 blocks, 128 thr (2 waves).
// Block: 32 q-rows (wave w: 16), 64-key chunks with kt%4==s, shared LDS K/V
// (pitch 72), register-prefetched. Partials (m,l,O) -> ws.
#define KP 72
__global__ __launch_bounds__(128) void attn_part(
    const ushort_t* __restrict__ q, const ushort_t* __restrict__ k,
    const ushort_t* __restrict__ vT, float* __restrict__ ML, ushort_t* __restrict__ OP)
{
  __shared__ __align__(16) ushort_t sK[64 * KP];     // [key][d]
  __shared__ __align__(16) ushort_t sV[64 * KP];     // [d][key]
  __shared__ __align__(16) ushort_t sP[2][16 * KP];  // per-wave P

  const int idx  = blockIdx.x;
  const int s    = idx & 3;
  const int b    = (idx >> 2) & 3;
  const int jt   = 127 - (idx >> 4);           // descending work order
  const int tid  = threadIdx.x;
  const int w    = tid >> 6;
  const int lane = tid & 63;
  const int l16  = lane & 15, quad = lane >> 4;
  const int R0   = jt * 32 + w * 16;

  const ushort_t* qg = q  + (size_t)b * TSEQ * HS;
  const ushort_t* kg = k  + (size_t)b * TSEQ * HS;
  const ushort_t* vg = vT + (size_t)b * HS * TSEQ;

  // Q B-operand frags (q pre-scaled 1/8): B[k=d][n=qrow]
  const short8 qf0 = *(const short8*)(qg + (R0 + l16) * HS +      quad * 8);
  const short8 qf1 = *(const short8*)(qg + (R0 + l16) * HS + 32 + quad * 8);

  f32x4 o[4];
#pragma unroll
  for (int dt = 0; dt < 4; dt++) o[dt] = (f32x4){0.f, 0.f, 0.f, 0.f};
  float mrow = -INFINITY, lrow = 0.f;          // per-lane qrow = R0 + l16

  const int nkt = jt / 2 + 1;                  // 64-key chunks incl. diagonal
  short8 kpre[4], vpre[4];
  int kt = s;
  if (kt < nkt) {
    const int k0 = kt * 64;
#pragma unroll
    for (int i = 0; i < 4; i++) {
      const int c = i * 128 + tid, key = c >> 3, ch = c & 7;
      kpre[i] = *(const short8*)(kg + (size_t)(k0 + key) * HS + ch * 8);
      vpre[i] = *(const short8*)(vg + (size_t)key * TSEQ + k0 + ch * 8);
    }
  }
  for (; kt < nkt; kt += KSPLIT) {
    const int k0 = kt * 64;
    __syncthreads();                           // prior iter's LDS reads done
#pragma unroll
    for (int i = 0; i < 4; i++) {
      const int c = i * 128 + tid, key = c >> 3, ch = c & 7;
      *(short8*)(sK + key * KP + ch * 8) = kpre[i];
      *(short8*)(sV + key * KP + ch * 8) = vpre[i];
    }
    if (kt + KSPLIT < nkt) {                   // prefetch next chunk
      const int kn = (kt + KSPLIT) * 64;
#pragma unroll
      for (int i = 0; i < 4; i++) {
        const int c = i * 128 + tid, key = c >> 3, ch = c & 7;
        kpre[i] = *(const short8*)(kg + (size_t)(kn + key) * HS + ch * 8);
        vpre[i] = *(const short8*)(vg + (size_t)key * TSEQ + kn + ch * 8);
      }
    }
    __syncthreads();                           // staged tile visible
    // ---- S^T = K Q^T : C[key = ct*16+quad*4+r][qrow = l16] ----
    f32x4 sT[4];
#pragma unroll
    for (int ct = 0; ct < 4; ct++) {
      sT[ct] = (f32x4){0.f, 0.f, 0.f, 0.f};
      const short8 kfa = *(const short8*)(sK + (ct * 16 + l16) * KP +      quad * 8);
      const short8 kfb = *(const short8*)(sK + (ct * 16 + l16) * KP + 32 + quad * 8);
      sT[ct] = MFMA16(kfa, qf0, sT[ct]);
      sT[ct] = MFMA16(kfb, qf1, sT[ct]);
    }
    if (k0 + 63 > R0) {                        // causal mask, diagonal only
      const int qrow = R0 + l16;
#pragma unroll
      for (int ct = 0; ct < 4; ct++)
#pragma unroll
        for (int r = 0; r < 4; r++)
          sT[ct][r] = (k0 + ct * 16 + quad * 4 + r <= qrow) ? sT[ct][r] : -INFINITY;
    }
    // ---- online softmax (per-lane row; 2 cross-quad shuffles) ----
    float tm = -INFINITY;
#pragma unroll
    for (int ct = 0; ct < 4; ct++)
#pragma unroll
      for (int r = 0; r < 4; r++) tm = fmaxf(tm, sT[ct][r]);
    tm = fmaxf(tm, __shfl_xor(tm, 16));
    tm = fmaxf(tm, __shfl_xor(tm, 32));
    const float mn = fmaxf(mrow, tm);
    const float al = __expf(mrow - mn);
    mrow = mn;
    float ps = 0.f;
#pragma unroll
    for (int ct = 0; ct < 4; ct++)
#pragma unroll
      for (int r = 0; r < 4; r++) { sT[ct][r] = __expf(sT[ct][r] - mn); ps += sT[ct][r]; }
    ps += __shfl_xor(ps, 16);
    ps += __shfl_xor(ps, 32);
    lrow = lrow * al + ps;
    // ---- P -> LDS (A-layout), O rescale, PV ----
    ushort_t* Pw = &sP[w][0];
#pragma unroll
    for (int ct = 0; ct < 4; ct++) {
      ushort4 pk;
      pk.x = f2bf(sT[ct][0]); pk.y = f2bf(sT[ct][1]);
      pk.z = f2bf(sT[ct][2]); pk.w = f2bf(sT[ct][3]);
      *(ushort4*)(Pw + l16 * KP + ct * 16 + quad * 4) = pk;
    }
    float alo[4];
#pragma unroll
    for (int r = 0; r < 4; r++) alo[r] = __shfl(al, quad * 4 + r);
#pragma unroll
    for (int dt = 0; dt < 4; dt++)
#pragma unroll
      for (int r = 0; r < 4; r++) o[dt][r] *= alo[r];
    const short8 pf0 = *(const short8*)(Pw + l16 * KP +      quad * 8);
    const short8 pf1 = *(const short8*)(Pw + l16 * KP + 32 + quad * 8);
#pragma unroll
    for (int dt = 0; dt < 4; dt++) {
      const short8 vfa = *(const short8*)(sV + (dt * 16 + l16) * KP +      quad * 8);
      const short8 vfb = *(const short8*)(sV + (dt * 16 + l16) * KP + 32 + quad * 8);
      o[dt] = MFMA16(pf0, vfa, o[dt]);
      o[dt] = MFMA16(pf1, vfb, o[dt]);
    }
  }

  // ---- write partials: ML fp32 [B][KSPLIT][T][2], OP bf16 [B][KSPLIT][T][64] ----
  const size_t base = ((size_t)(b * KSPLIT + s) * TSEQ);
  if (quad == 0) {
    ML[(base + R0 + l16) * 2 + 0] = mrow;
    ML[(base + R0 + l16) * 2 + 1] = lrow;
  }
#pragma unroll
  for (int dt = 0; dt < 4; dt++)
#pragma unroll
    for (int r = 0; r < 4; r++)
      OP[(base + R0 + quad * 4 + r) * HS + dt * 16 + l16] = f2bf(o[dt][r]);
}

// ---------------- attention pass 2: merge the KSPLIT partials ----------------
// grid 1024 x 256: block = 16 rows x 16 dim-groups.
__global__ __launch_bounds__(256) void attn_merge(
    const float* __restrict__ ML, const ushort_t* __restrict__ OP,
    float* __restrict__ out)
{
  const int row = blockIdx.x * 16 + (threadIdx.x >> 4);   // 0..16383
  const int b   = row >> 12, t = row & (TSEQ - 1);
  const int d0  = (threadIdx.x & 15) * 4;
  float m[KSPLIT], l[KSPLIT];
  float M = -INFINITY;
#pragma unroll
  for (int ss = 0; ss < KSPLIT; ss++) {
    const size_t i = ((size_t)(b * KSPLIT + ss) * TSEQ + t);
    m[ss] = ML[i * 2]; l[ss] = ML[i * 2 + 1];
    M = fmaxf(M, m[ss]);
  }
  float den = 0.f;
  float4 num = make_float4(0.f, 0.f, 0.f, 0.f);
#pragma unroll
  for (int ss = 0; ss < KSPLIT; ss++) {
    const float a = __expf(m[ss] - M);          // zero-trip split: weight 0
    den += l[ss] * a;
    const size_t i = ((size_t)(b * KSPLIT + ss) * TSEQ + t);
    const ushort4 u = *(const ushort4*)(OP + i * HS + d0);
    num.x += a * bf2f(u.x); num.y += a * bf2f(u.y);
    num.z += a * bf2f(u.z); num.w += a * bf2f(u.w);
  }
  const float inv = 1.f / den;
  *(float4*)(out + (size_t)row * HS + d0) =
      make_float4(num.x * inv, num.y * inv, num.z * inv, num.w * inv);
}

extern "C" void kernel_launch(void* const* d_in, const int* in_sizes, int n_in,
                              void* d_out, int out_size, void* d_ws, size_t ws_size,
                              hipStream_t stream) {
  const float* x  = (const float*)d_in[0];
  const float* Wq = (const float*)d_in[1];
  const float* Wk = (const float*)d_in[2];
  const float* Wv = (const float*)d_in[3];
  float* out = (float*)d_out;

  // ws: Wt 288K | q 2M | k 2M | vT 2M | ML 512K | OP 8M   (total ~15 MB)
  char* ws = (char*)d_ws;
  ushort_t* Wt = (ushort_t*)ws;
  ushort_t* qb = (ushort_t*)(ws + 294912);
  ushort_t* kb = (ushort_t*)(ws + 294912 + 2097152);
  ushort_t* vb = (ushort_t*)(ws + 294912 + 2 * 2097152);
  float*    ml = (float*)   (ws + 294912 + 3 * 2097152);
  ushort_t* op = (ushort_t*)(ws + 294912 + 3 * 2097152 + 524288);

  wprep<<<36, 256, 0, stream>>>(Wq, Wk, Wv, Wt);
  qkv_mfma<<<(NBATCH * TSEQ) / 16, 256, 0, stream>>>(x, Wt, qb, kb, vb);
  attn_part<<<128 * NBATCH * KSPLIT, 128, 0, stream>>>(qb, kb, vb, ml, op);
  attn_merge<<<1024, 256, 0, stream>>>(ml, op, out);
}

// Round 5
// 131.054 us; speedup vs baseline: 1.2698x; 1.1593x over previous
//
#include <hip/hip_runtime.h>
#include <math.h>

typedef __attribute__((ext_vector_type(8))) short short8;
typedef __attribute__((ext_vector_type(4))) float f32x4;
typedef unsigned short ushort_t;

#define TSEQ   4096
#define NBATCH 4
#define DMODEL 768
#define HS     64
#define KSPLIT 4

static __device__ __forceinline__ ushort_t f2bf(float f) {
  union { float f; unsigned u; } v; v.f = f;
  unsigned r = v.u + 0x7fffu + ((v.u >> 16) & 1u);   // RNE
  return (ushort_t)(r >> 16);
}
static __device__ __forceinline__ float bf2f(ushort_t u) {
  union { unsigned u; float f; } v; v.u = ((unsigned)u) << 16; return v.f;
}

#define MFMA16(a,b,c) __builtin_amdgcn_mfma_f32_16x16x32_bf16((a),(b),(c),0,0,0)

// ---------------- W prep (coalesced LDS transpose) ----------------
// grid 36 = 3 mats x 12 k-chunks of 64.  Wt[n'=m*64+n][k] bf16.
__global__ __launch_bounds__(256) void wprep(
    const float* __restrict__ Wq, const float* __restrict__ Wk,
    const float* __restrict__ Wv, ushort_t* __restrict__ Wt)
{
  __shared__ float lds[64 * 65];
  const int m = blockIdx.x / 12, kc = blockIdx.x % 12, k0 = kc * 64;
  const float* W = (m == 0) ? Wq : (m == 1) ? Wk : Wv;
  const int tid = threadIdx.x;
#pragma unroll
  for (int i = 0; i < 16; i++) {
    const int row = i * 4 + (tid >> 6), col = tid & 63;
    lds[row * 65 + col] = W[(size_t)(k0 + row) * HS + col];   // coalesced
  }
  __syncthreads();
#pragma unroll
  for (int i = 0; i < 16; i++) {
    const int n = i * 4 + (tid >> 6), kk = tid & 63;
    Wt[(size_t)(m * 64 + n) * DMODEL + k0 + kk] = f2bf(lds[kk * 65 + n]);
  }
}

// ---------------- QKV projection: dual-LDS double-buffered GEMM ----------
// Round-9 diagnosis: rounds 1/4 were LATENCY-SERIALIZED on the B-operand --
// the allocator refuses to keep 6 register-prefetch loads in flight
// (VGPR=36/68), emitting load->wait->use chains: ~2.6k cy per K-step of
// pure L2/L3 latency (measured 31k cy/block), with MfmaUtil ~3%.
// Fix: B in LDS via global_load_lds (in-flight costs ZERO VGPRs, drained
// one full compute-phase later by the next barrier = m97-proven pipeline).
// A is reg-staged fp32->bf16 ONCE per element (4 elems/thread/ks) into
// pitch-72 LDS (conflict-free, round-0-proven).  sB uses the both-sides
// XOR swizzle k^=((col&7)<<3): pre-swizzled GLOBAL source + swizzled read,
// LDS linear (global_load_lds writes base+lane*16 only).  BM=32, BN=192,
// BK=64: 512 blocks x 4 waves (wave = 32r x 48c, 12 MFMA/ks), 58 KB LDS,
// 2 blocks/CU -- all 512 resident, one barrier per K-step.
__global__ __launch_bounds__(256, 2) void qkv_mfma(
    const float* __restrict__ x, const ushort_t* __restrict__ Wt,
    ushort_t* __restrict__ q, ushort_t* __restrict__ kO, ushort_t* __restrict__ vT)
{
  __shared__ __align__(16) ushort_t sA[2][32 * 72];    //  9.2 KB
  __shared__ __align__(16) ushort_t sB[2][192 * 64];   // 48.0 KB

  const int tid  = threadIdx.x;
  const int w    = tid >> 6;                    // wave id = col split 0..3
  const int lane = tid & 63;
  const int l16  = lane & 15, quad = lane >> 4;
  const int M0   = blockIdx.x * 32;

  // A staging role: thread t covers row t/8, k-chunk (t%8)*8 (2 float4)
  const int arow = tid >> 3, acol = (tid & 7) * 8;
  const float* ax = x + (size_t)(M0 + arow) * DMODEL + acol;

  // B staging role: wave w stages its own 48 cols, 6 x 1KB issues.
  // Pre-swizzled global k-offset so (linear LDS dest, swizzled read) match:
  // lane l covers col w*48+j*8+(l>>3), LDS slot (l&7)*8, global k = slot^((col&7)*8)
  const int bcol_l = lane >> 3;                               // 0..7
  const int bkoff  = (((lane & 7) ^ (bcol_l & 7)) << 3);      // elems

  f32x4 acc[2][3];
#pragma unroll
  for (int mt = 0; mt < 2; mt++)
#pragma unroll
    for (int nt = 0; nt < 3; nt++) acc[mt][nt] = (f32x4){0.f, 0.f, 0.f, 0.f};

  // ---- prologue: stage tile 0 into buf 0
  {
#pragma unroll
    for (int j = 0; j < 6; j++) {
      const int colb = w * 48 + j * 8;
      __builtin_amdgcn_global_load_lds(
          (const __attribute__((address_space(1))) ushort_t*)
              (Wt + (size_t)(colb + bcol_l) * DMODEL + bkoff),
          (__attribute__((address_space(3))) ushort_t*)(&sB[0][colb * 64]),
          16, 0, 0);
    }
    const float4 f0 = *(const float4*)(ax);
    const float4 f1 = *(const float4*)(ax + 4);
    short8 p;
    p[0]=f2bf(f0.x); p[1]=f2bf(f0.y); p[2]=f2bf(f0.z); p[3]=f2bf(f0.w);
    p[4]=f2bf(f1.x); p[5]=f2bf(f1.y); p[6]=f2bf(f1.z); p[7]=f2bf(f1.w);
    *(short8*)(&sA[0][arow * 72 + acol]) = p;
  }

  for (int ks = 0; ks < DMODEL / 64; ks++) {
    const int cur = ks & 1, nxt = cur ^ 1;
    __syncthreads();          // buf[cur] ready (drains prior gll + ds_write)

    float4 f0n, f1n;
    if (ks < DMODEL / 64 - 1) {
      // issue next B tile (async; drains at NEXT barrier, hidden under MFMA)
#pragma unroll
      for (int j = 0; j < 6; j++) {
        const int colb = w * 48 + j * 8;
        __builtin_amdgcn_global_load_lds(
            (const __attribute__((address_space(1))) ushort_t*)
                (Wt + (size_t)(colb + bcol_l) * DMODEL + (ks + 1) * 64 + bkoff),
            (__attribute__((address_space(3))) ushort_t*)(&sB[nxt][colb * 64]),
            16, 0, 0);
      }
      // issue next A loads (2 float4/thread; consumed after compute)
      f0n = *(const float4*)(ax + (ks + 1) * 64);
      f1n = *(const float4*)(ax + (ks + 1) * 64 + 4);
    }

    // ---- compute from buf[cur]
    const ushort_t* sAc = &sA[cur][0];
    const ushort_t* sBc = &sB[cur][0];
#pragma unroll
    for (int kc = 0; kc < 2; kc++) {
      const short8 a0 = *(const short8*)(sAc + (l16)      * 72 + kc * 32 + quad * 8);
      const short8 a1 = *(const short8*)(sAc + (16 + l16) * 72 + kc * 32 + quad * 8);
      const int kswz = (kc * 32 + quad * 8) ^ ((l16 & 7) << 3);
#pragma unroll
      for (int nt = 0; nt < 3; nt++) {
        const short8 bf =
            *(const short8*)(sBc + (w * 48 + nt * 16 + l16) * 64 + kswz);
        acc[0][nt] = MFMA16(a0, bf, acc[0][nt]);
        acc[1][nt] = MFMA16(a1, bf, acc[1][nt]);
      }
    }

    if (ks < DMODEL / 64 - 1) {          // convert + stage next A tile
      short8 p;
      p[0]=f2bf(f0n.x); p[1]=f2bf(f0n.y); p[2]=f2bf(f0n.z); p[3]=f2bf(f0n.w);
      p[4]=f2bf(f1n.x); p[5]=f2bf(f1n.y); p[6]=f2bf(f1n.z); p[7]=f2bf(f1n.w);
      *(short8*)(&sA[nxt][arow * 72 + acol]) = p;
    }
  }

  // ---- epilogue: q/k direct; v via LDS transpose ----
#pragma unroll
  for (int mt = 0; mt < 2; mt++)
#pragma unroll
    for (int nt = 0; nt < 3; nt++) {
      const int gnt = w * 3 + nt;               // 0..11
      const int mat = gnt >> 2;                 // 0=q 1=k 2=v (wave-uniform)
      const int col = (gnt & 3) * 16 + l16;
      if (mat == 0) {
#pragma unroll
        for (int r = 0; r < 4; r++)
          q[(size_t)(M0 + mt * 16 + quad * 4 + r) * HS + col] =
              f2bf(acc[mt][nt][r] * 0.125f);
      } else if (mat == 1) {
#pragma unroll
        for (int r = 0; r < 4; r++)
          kO[(size_t)(M0 + mt * 16 + quad * 4 + r) * HS + col] =
              f2bf(acc[mt][nt][r]);
      }
    }
  __syncthreads();                              // K-loop LDS reads done
  float* vls = (float*)&sA[0][0];               // [32][65] fp32 = 8.3 KB
#pragma unroll
  for (int mt = 0; mt < 2; mt++)
#pragma unroll
    for (int nt = 0; nt < 3; nt++) {
      const int gnt = w * 3 + nt;
      if ((gnt >> 2) == 2) {
        const int vcol = (gnt & 3) * 16 + l16;
#pragma unroll
        for (int r = 0; r < 4; r++)
          vls[(mt * 16 + quad * 4 + r) * 65 + vcol] = acc[mt][nt][r];
      }
    }
  __syncthreads();
  const int d = tid >> 2, seg = tid & 3;        // 64 dims x 4 segs of 8 t
  short8 pk;
#pragma unroll
  for (int i = 0; i < 8; i++) pk[i] = (short)f2bf(vls[(seg * 8 + i) * 65 + d]);
  *(short8*)(vT + ((size_t)(M0 >> 12) * HS + d) * TSEQ + (M0 & (TSEQ - 1)) + seg * 8) = pk;
}

// ---------------- attention pass 1: partial flash attention ----------------
// grid = 128 jt (descending) x B x KSPLIT(4) = 2048 blocks, 128 thr (2 waves).
// Block: 32 q-rows (wave w: 16), 64-key chunks with kt%4==s, shared LDS K/V
// (pitch 72), register-prefetched. Partials (m,l,O) -> ws.
#define KP 72
__global__ __launch_bounds__(128) void attn_part(
    const ushort_t* __restrict__ q, const ushort_t* __restrict__ k,
    const ushort_t* __restrict__ vT, float* __restrict__ ML, ushort_t* __restrict__ OP)
{
  __shared__ __align__(16) ushort_t sK[64 * KP];     // [key][d]
  __shared__ __align__(16) ushort_t sV[64 * KP];     // [d][key]
  __shared__ __align__(16) ushort_t sP[2][16 * KP];  // per-wave P

  const int idx  = blockIdx.x;
  const int s    = idx & 3;
  const int b    = (idx >> 2) & 3;
  const int jt   = 127 - (idx >> 4);           // descending work order
  const int tid  = threadIdx.x;
  const int w    = tid >> 6;
  const int lane = tid & 63;
  const int l16  = lane & 15, quad = lane >> 4;
  const int R0   = jt * 32 + w * 16;

  const ushort_t* qg = q  + (size_t)b * TSEQ * HS;
  const ushort_t* kg = k  + (size_t)b * TSEQ * HS;
  const ushort_t* vg = vT + (size_t)b * HS * TSEQ;

  // Q B-operand frags (q pre-scaled 1/8): B[k=d][n=qrow]
  const short8 qf0 = *(const short8*)(qg + (R0 + l16) * HS +      quad * 8);
  const short8 qf1 = *(const short8*)(qg + (R0 + l16) * HS + 32 + quad * 8);

  f32x4 o[4];
#pragma unroll
  for (int dt = 0; dt < 4; dt++) o[dt] = (f32x4){0.f, 0.f, 0.f, 0.f};
  float mrow = -INFINITY, lrow = 0.f;          // per-lane qrow = R0 + l16

  const int nkt = jt / 2 + 1;                  // 64-key chunks incl. diagonal
  short8 kpre[4], vpre[4];
  int kt = s;
  if (kt < nkt) {
    const int k0 = kt * 64;
#pragma unroll
    for (int i = 0; i < 4; i++) {
      const int c = i * 128 + tid, key = c >> 3, ch = c & 7;
      kpre[i] = *(const short8*)(kg + (size_t)(k0 + key) * HS + ch * 8);
      vpre[i] = *(const short8*)(vg + (size_t)key * TSEQ + k0 + ch * 8);
    }
  }
  for (; kt < nkt; kt += KSPLIT) {
    const int k0 = kt * 64;
    __syncthreads();                           // prior iter's LDS reads done
#pragma unroll
    for (int i = 0; i < 4; i++) {
      const int c = i * 128 + tid, key = c >> 3, ch = c & 7;
      *(short8*)(sK + key * KP + ch * 8) = kpre[i];
      *(short8*)(sV + key * KP + ch * 8) = vpre[i];
    }
    if (kt + KSPLIT < nkt) {                   // prefetch next chunk
      const int kn = (kt + KSPLIT) * 64;
#pragma unroll
      for (int i = 0; i < 4; i++) {
        const int c = i * 128 + tid, key = c >> 3, ch = c & 7;
        kpre[i] = *(const short8*)(kg + (size_t)(kn + key) * HS + ch * 8);
        vpre[i] = *(const short8*)(vg + (size_t)key * TSEQ + kn + ch * 8);
      }
    }
    __syncthreads();                           // staged tile visible
    // ---- S^T = K Q^T : C[key = ct*16+quad*4+r][qrow = l16] ----
    f32x4 sT[4];
#pragma unroll
    for (int ct = 0; ct < 4; ct++) {
      sT[ct] = (f32x4){0.f, 0.f, 0.f, 0.f};
      const short8 kfa = *(const short8*)(sK + (ct * 16 + l16) * KP +      quad * 8);
      const short8 kfb = *(const short8*)(sK + (ct * 16 + l16) * KP + 32 + quad * 8);
      sT[ct] = MFMA16(kfa, qf0, sT[ct]);
      sT[ct] = MFMA16(kfb, qf1, sT[ct]);
    }
    if (k0 + 63 > R0) {                        // causal mask, diagonal only
      const int qrow = R0 + l16;
#pragma unroll
      for (int ct = 0; ct < 4; ct++)
#pragma unroll
        for (int r = 0; r < 4; r++)
          sT[ct][r] = (k0 + ct * 16 + quad * 4 + r <= qrow) ? sT[ct][r] : -INFINITY;
    }
    // ---- online softmax (per-lane row; 2 cross-quad shuffles) ----
    float tm = -INFINITY;
#pragma unroll
    for (int ct = 0; ct < 4; ct++)
#pragma unroll
      for (int r = 0; r < 4; r++) tm = fmaxf(tm, sT[ct][r]);
    tm = fmaxf(tm, __shfl_xor(tm, 16));
    tm = fmaxf(tm, __shfl_xor(tm, 32));
    const float mn = fmaxf(mrow, tm);
    const float al = __expf(mrow - mn);
    mrow = mn;
    float ps = 0.f;
#pragma unroll
    for (int ct = 0; ct < 4; ct++)
#pragma unroll
      for (int r = 0; r < 4; r++) { sT[ct][r] = __expf(sT[ct][r] - mn); ps += sT[ct][r]; }
    ps += __shfl_xor(ps, 16);
    ps += __shfl_xor(ps, 32);
    lrow = lrow * al + ps;
    // ---- P -> LDS (A-layout), O rescale, PV ----
    ushort_t* Pw = &sP[w][0];
#pragma unroll
    for (int ct = 0; ct < 4; ct++) {
      ushort4 pk;
      pk.x = f2bf(sT[ct][0]); pk.y = f2bf(sT[ct][1]);
      pk.z = f2bf(sT[ct][2]); pk.w = f2bf(sT[ct][3]);
      *(ushort4*)(Pw + l16 * KP + ct * 16 + quad * 4) = pk;
    }
    float alo[4];
#pragma unroll
    for (int r = 0; r < 4; r++) alo[r] = __shfl(al, quad * 4 + r);
#pragma unroll
    for (int dt = 0; dt < 4; dt++)
#pragma unroll
      for (int r = 0; r < 4; r++) o[dt][r] *= alo[r];
    const short8 pf0 = *(const short8*)(Pw + l16 * KP +      quad * 8);
    const short8 pf1 = *(const short8*)(Pw + l16 * KP + 32 + quad * 8);
#pragma unroll
    for (int dt = 0; dt < 4; dt++) {
      const short8 vfa = *(const short8*)(sV + (dt * 16 + l16) * KP +      quad * 8);
      const short8 vfb = *(const short8*)(sV + (dt * 16 + l16) * KP + 32 + quad * 8);
      o[dt] = MFMA16(pf0, vfa, o[dt]);
      o[dt] = MFMA16(pf1, vfb, o[dt]);
    }
  }

  // ---- write partials: ML fp32 [B][KSPLIT][T][2], OP bf16 [B][KSPLIT][T][64] ----
  const size_t base = ((size_t)(b * KSPLIT + s) * TSEQ);
  if (quad == 0) {
    ML[(base + R0 + l16) * 2 + 0] = mrow;
    ML[(base + R0 + l16) * 2 + 1] = lrow;
  }
#pragma unroll
  for (int dt = 0; dt < 4; dt++)
#pragma unroll
    for (int r = 0; r < 4; r++)
      OP[(base + R0 + quad * 4 + r) * HS + dt * 16 + l16] = f2bf(o[dt][r]);
}

// ---------------- attention pass 2: merge the KSPLIT partials ----------------
// grid 1024 x 256: block = 16 rows x 16 dim-groups.
__global__ __launch_bounds__(256) void attn_merge(
    const float* __restrict__ ML, const ushort_t* __restrict__ OP,
    float* __restrict__ out)
{
  const int row = blockIdx.x * 16 + (threadIdx.x >> 4);   // 0..16383
  const int b   = row >> 12, t = row & (TSEQ - 1);
  const int d0  = (threadIdx.x & 15) * 4;
  float m[KSPLIT], l[KSPLIT];
  float M = -INFINITY;
#pragma unroll
  for (int ss = 0; ss < KSPLIT; ss++) {
    const size_t i = ((size_t)(b * KSPLIT + ss) * TSEQ + t);
    m[ss] = ML[i * 2]; l[ss] = ML[i * 2 + 1];
    M = fmaxf(M, m[ss]);
  }
  float den = 0.f;
  float4 num = make_float4(0.f, 0.f, 0.f, 0.f);
#pragma unroll
  for (int ss = 0; ss < KSPLIT; ss++) {
    const float a = __expf(m[ss] - M);          // zero-trip split: weight 0
    den += l[ss] * a;
    const size_t i = ((size_t)(b * KSPLIT + ss) * TSEQ + t);
    const ushort4 u = *(const ushort4*)(OP + i * HS + d0);
    num.x += a * bf2f(u.x); num.y += a * bf2f(u.y);
    num.z += a * bf2f(u.z); num.w += a * bf2f(u.w);
  }
  const float inv = 1.f / den;
  *(float4*)(out + (size_t)row * HS + d0) =
      make_float4(num.x * inv, num.y * inv, num.z * inv, num.w * inv);
}

extern "C" void kernel_launch(void* const* d_in, const int* in_sizes, int n_in,
                              void* d_out, int out_size, void* d_ws, size_t ws_size,
                              hipStream_t stream) {
  const float* x  = (const float*)d_in[0];
  const float* Wq = (const float*)d_in[1];
  const float* Wk = (const float*)d_in[2];
  const float* Wv = (const float*)d_in[3];
  float* out = (float*)d_out;

  // ws: Wt 288K | q 2M | k 2M | vT 2M | ML 512K | OP 8M   (total ~15 MB)
  char* ws = (char*)d_ws;
  ushort_t* Wt = (ushort_t*)ws;
  ushort_t* qb = (ushort_t*)(ws + 294912);
  ushort_t* kb = (ushort_t*)(ws + 294912 + 2097152);
  ushort_t* vb = (ushort_t*)(ws + 294912 + 2 * 2097152);
  float*    ml = (float*)   (ws + 294912 + 3 * 2097152);
  ushort_t* op = (ushort_t*)(ws + 294912 + 3 * 2097152 + 524288);

  wprep<<<36, 256, 0, stream>>>(Wq, Wk, Wv, Wt);
  qkv_mfma<<<(NBATCH * TSEQ) / 32, 256, 0, stream>>>(x, Wt, qb, kb, vb);
  attn_part<<<128 * NBATCH * KSPLIT, 128, 0, stream>>>(qb, kb, vb, ml, op);
  attn_merge<<<1024, 256, 0, stream>>>(ml, op, out);
}

// Round 6
// 127.991 us; speedup vs baseline: 1.3002x; 1.0239x over previous
//
#include <hip/hip_runtime.h>
#include <math.h>

typedef __attribute__((ext_vector_type(8))) short short8;
typedef __attribute__((ext_vector_type(4))) float f32x4;
typedef unsigned short ushort_t;

#define TSEQ   4096
#define NBATCH 4
#define DMODEL 768
#define HS     64
#define KSPLIT 4

static __device__ __forceinline__ ushort_t f2bf(float f) {
  union { float f; unsigned u; } v; v.f = f;
  unsigned r = v.u + 0x7fffu + ((v.u >> 16) & 1u);   // RNE
  return (ushort_t)(r >> 16);
}
static __device__ __forceinline__ float bf2f(ushort_t u) {
  union { unsigned u; float f; } v; v.u = ((unsigned)u) << 16; return v.f;
}

#define MFMA16(a,b,c) __builtin_amdgcn_mfma_f32_16x16x32_bf16((a),(b),(c),0,0,0)

// ---------------- W prep (coalesced LDS transpose) ----------------
// grid 36 = 3 mats x 12 k-chunks of 64.  Wt[n'=m*64+n][k] bf16.
__global__ __launch_bounds__(256) void wprep(
    const float* __restrict__ Wq, const float* __restrict__ Wk,
    const float* __restrict__ Wv, ushort_t* __restrict__ Wt)
{
  __shared__ float lds[64 * 65];
  const int m = blockIdx.x / 12, kc = blockIdx.x % 12, k0 = kc * 64;
  const float* W = (m == 0) ? Wq : (m == 1) ? Wk : Wv;
  const int tid = threadIdx.x;
#pragma unroll
  for (int i = 0; i < 16; i++) {
    const int row = i * 4 + (tid >> 6), col = tid & 63;
    lds[row * 65 + col] = W[(size_t)(k0 + row) * HS + col];   // coalesced
  }
  __syncthreads();
#pragma unroll
  for (int i = 0; i < 16; i++) {
    const int n = i * 4 + (tid >> 6), kk = tid & 63;
    Wt[(size_t)(m * 64 + n) * DMODEL + k0 + kk] = f2bf(lds[kk * 65 + n]);
  }
}

// ---------------- QKV projection: dual-LDS double-buffered GEMM ----------
// Round-5 structure (won: 52 -> ~31 us).  Round-6 change: epilogue writes
// k and vT in ROW-XOR-SWIZZLED layouts (16B-block index ^= row&7) so
// attn_part can stage them with linear global_load_lds and still read
// bank-conflict-free (both-sides swizzle rule).  Layouts private to us.
__global__ __launch_bounds__(256, 2) void qkv_mfma(
    const float* __restrict__ x, const ushort_t* __restrict__ Wt,
    ushort_t* __restrict__ q, ushort_t* __restrict__ kO, ushort_t* __restrict__ vT)
{
  __shared__ __align__(16) ushort_t sA[2][32 * 72];    //  9.2 KB
  __shared__ __align__(16) ushort_t sB[2][192 * 64];   // 48.0 KB

  const int tid  = threadIdx.x;
  const int w    = tid >> 6;                    // wave id = col split 0..3
  const int lane = tid & 63;
  const int l16  = lane & 15, quad = lane >> 4;
  const int M0   = blockIdx.x * 32;

  // A staging role: thread t covers row t/8, k-chunk (t%8)*8 (2 float4)
  const int arow = tid >> 3, acol = (tid & 7) * 8;
  const float* ax = x + (size_t)(M0 + arow) * DMODEL + acol;

  // B staging role: pre-swizzled global k-offset (linear LDS dest + swz read)
  const int bcol_l = lane >> 3;                               // 0..7
  const int bkoff  = (((lane & 7) ^ (bcol_l & 7)) << 3);      // elems

  f32x4 acc[2][3];
#pragma unroll
  for (int mt = 0; mt < 2; mt++)
#pragma unroll
    for (int nt = 0; nt < 3; nt++) acc[mt][nt] = (f32x4){0.f, 0.f, 0.f, 0.f};

  // ---- prologue: stage tile 0 into buf 0
  {
#pragma unroll
    for (int j = 0; j < 6; j++) {
      const int colb = w * 48 + j * 8;
      __builtin_amdgcn_global_load_lds(
          (const __attribute__((address_space(1))) ushort_t*)
              (Wt + (size_t)(colb + bcol_l) * DMODEL + bkoff),
          (__attribute__((address_space(3))) ushort_t*)(&sB[0][colb * 64]),
          16, 0, 0);
    }
    const float4 f0 = *(const float4*)(ax);
    const float4 f1 = *(const float4*)(ax + 4);
    short8 p;
    p[0]=f2bf(f0.x); p[1]=f2bf(f0.y); p[2]=f2bf(f0.z); p[3]=f2bf(f0.w);
    p[4]=f2bf(f1.x); p[5]=f2bf(f1.y); p[6]=f2bf(f1.z); p[7]=f2bf(f1.w);
    *(short8*)(&sA[0][arow * 72 + acol]) = p;
  }

  for (int ks = 0; ks < DMODEL / 64; ks++) {
    const int cur = ks & 1, nxt = cur ^ 1;
    __syncthreads();          // buf[cur] ready (drains prior gll + ds_write)

    float4 f0n, f1n;
    if (ks < DMODEL / 64 - 1) {
#pragma unroll
      for (int j = 0; j < 6; j++) {
        const int colb = w * 48 + j * 8;
        __builtin_amdgcn_global_load_lds(
            (const __attribute__((address_space(1))) ushort_t*)
                (Wt + (size_t)(colb + bcol_l) * DMODEL + (ks + 1) * 64 + bkoff),
            (__attribute__((address_space(3))) ushort_t*)(&sB[nxt][colb * 64]),
            16, 0, 0);
      }
      f0n = *(const float4*)(ax + (ks + 1) * 64);
      f1n = *(const float4*)(ax + (ks + 1) * 64 + 4);
    }

    // ---- compute from buf[cur]
    const ushort_t* sAc = &sA[cur][0];
    const ushort_t* sBc = &sB[cur][0];
#pragma unroll
    for (int kc = 0; kc < 2; kc++) {
      const short8 a0 = *(const short8*)(sAc + (l16)      * 72 + kc * 32 + quad * 8);
      const short8 a1 = *(const short8*)(sAc + (16 + l16) * 72 + kc * 32 + quad * 8);
      const int kswz = (kc * 32 + quad * 8) ^ ((l16 & 7) << 3);
#pragma unroll
      for (int nt = 0; nt < 3; nt++) {
        const short8 bf =
            *(const short8*)(sBc + (w * 48 + nt * 16 + l16) * 64 + kswz);
        acc[0][nt] = MFMA16(a0, bf, acc[0][nt]);
        acc[1][nt] = MFMA16(a1, bf, acc[1][nt]);
      }
    }

    if (ks < DMODEL / 64 - 1) {          // convert + stage next A tile
      short8 p;
      p[0]=f2bf(f0n.x); p[1]=f2bf(f0n.y); p[2]=f2bf(f0n.z); p[3]=f2bf(f0n.w);
      p[4]=f2bf(f1n.x); p[5]=f2bf(f1n.y); p[6]=f2bf(f1n.z); p[7]=f2bf(f1n.w);
      *(short8*)(&sA[nxt][arow * 72 + acol]) = p;
    }
  }

  // ---- epilogue: q direct; k swizzled; v via LDS transpose, swizzled ----
#pragma unroll
  for (int mt = 0; mt < 2; mt++)
#pragma unroll
    for (int nt = 0; nt < 3; nt++) {
      const int gnt = w * 3 + nt;               // 0..11
      const int mat = gnt >> 2;                 // 0=q 1=k 2=v (wave-uniform)
      if (mat == 0) {
        const int col = (gnt & 3) * 16 + l16;
#pragma unroll
        for (int r = 0; r < 4; r++)
          q[(size_t)(M0 + mt * 16 + quad * 4 + r) * HS + col] =
              f2bf(acc[mt][nt][r] * 0.125f);
      } else if (mat == 1) {
        // k: 16B-block index of col, XOR'd with trow&7 (attn-staging swizzle)
        const int cb2 = (gnt & 3) * 2 + (l16 >> 3);
#pragma unroll
        for (int r = 0; r < 4; r++) {
          const int trow  = M0 + mt * 16 + quad * 4 + r;
          const int cphys = ((cb2 ^ (trow & 7)) << 3) | (l16 & 7);
          kO[(size_t)trow * HS + cphys] = f2bf(acc[mt][nt][r]);
        }
      }
    }
  __syncthreads();                              // K-loop LDS reads done
  float* vls = (float*)&sA[0][0];               // [32][65] fp32 = 8.3 KB
#pragma unroll
  for (int mt = 0; mt < 2; mt++)
#pragma unroll
    for (int nt = 0; nt < 3; nt++) {
      const int gnt = w * 3 + nt;
      if ((gnt >> 2) == 2) {
        const int vcol = (gnt & 3) * 16 + l16;
#pragma unroll
        for (int r = 0; r < 4; r++)
          vls[(mt * 16 + quad * 4 + r) * 65 + vcol] = acc[mt][nt][r];
      }
    }
  __syncthreads();
  const int d = tid >> 2, seg = tid & 3;        // 64 dims x 4 segs of 8 t
  short8 pk;
#pragma unroll
  for (int i = 0; i < 8; i++) pk[i] = (short)f2bf(vls[(seg * 8 + i) * 65 + d]);
  // vT: key-block within 64-chunk XOR'd with d&7 (attn-staging swizzle)
  {
    const int t0  = M0 & (TSEQ - 1);
    const int tb  = t0 & ~63;
    const int kb  = ((t0 & 63) >> 3) + seg;
    const int kbp = kb ^ (d & 7);
    *(short8*)(vT + ((size_t)(M0 >> 12) * HS + d) * TSEQ + tb + kbp * 8) = pk;
  }
}

// ---------------- attention pass 1: partial flash attention ----------------
// Round-6 restructure (qkv-proven pattern ported): 256 thr / 4 waves per
// block, 64 q-rows (wave w: 16).  K/V double-buffered in LDS via
// global_load_lds (zero-VGPR async staging; the old kpre/vpre register
// prefetch was allocator-serialized like qkv rounds 1/4), ONE barrier per
// 64-key chunk.  K and vT arrive pre-swizzled from qkv (block^=row&7), so
// linear pitch-64 staging + XOR read is bank-conflict-free.  Chunk sets
// per q-row are identical to the old 2-wave version -> bit-identical math.
// grid 64 jt (descending) x B x KSPLIT = 1024 blocks; LDS 41.2 KB ->
// 3 blocks/CU, 12 waves/CU.
#define KP 72
__global__ __launch_bounds__(256, 3) void attn_part(
    const ushort_t* __restrict__ q, const ushort_t* __restrict__ k,
    const ushort_t* __restrict__ vT, float* __restrict__ ML, ushort_t* __restrict__ OP)
{
  __shared__ __align__(16) ushort_t sK[2][64 * 64];  // 16 KB  [key][d swz]
  __shared__ __align__(16) ushort_t sV[2][64 * 64];  // 16 KB  [d][key swz]
  __shared__ __align__(16) ushort_t sP[4][16 * KP];  //  9 KB  per-wave P

  const int idx  = blockIdx.x;
  const int s    = idx & 3;
  const int b    = (idx >> 2) & 3;
  const int jt   = 63 - (idx >> 4);            // descending work order
  const int tid  = threadIdx.x;
  const int w    = tid >> 6;
  const int lane = tid & 63;
  const int l16  = lane & 15, quad = lane >> 4;
  const int R0   = jt * 64 + w * 16;

  const ushort_t* qg = q  + (size_t)b * TSEQ * HS;
  const ushort_t* kg = k  + (size_t)b * TSEQ * HS;
  const ushort_t* vg = vT + (size_t)b * HS * TSEQ;

  // Q B-operand frags (q pre-scaled 1/8, unswizzled): B[k=d][n=qrow]
  const short8 qf0 = *(const short8*)(qg + (size_t)(R0 + l16) * HS +      quad * 8);
  const short8 qf1 = *(const short8*)(qg + (size_t)(R0 + l16) * HS + 32 + quad * 8);

  f32x4 o[4];
#pragma unroll
  for (int dt = 0; dt < 4; dt++) o[dt] = (f32x4){0.f, 0.f, 0.f, 0.f};
  float mrow = -INFINITY, lrow = 0.f;          // per-lane qrow = R0 + l16

  const int nkt = jt + 1;                      // 64-key chunks incl. diagonal
  const int srow = lane >> 3;                  // staging: 8 rows/issue
  const int scol = (lane & 7) * 8;

  int kt = s, cur = 0;
  if (kt < nkt) {                              // prologue: stage chunk kt->buf0
    const int k0 = kt * 64;
#pragma unroll
    for (int j = 0; j < 2; j++) {
      const int r0 = w * 16 + j * 8;
      __builtin_amdgcn_global_load_lds(
          (const __attribute__((address_space(1))) ushort_t*)
              (kg + (size_t)(k0 + r0 + srow) * HS + scol),
          (__attribute__((address_space(3))) ushort_t*)(&sK[0][r0 * 64]),
          16, 0, 0);
      __builtin_amdgcn_global_load_lds(
          (const __attribute__((address_space(1))) ushort_t*)
              (vg + (size_t)(r0 + srow) * TSEQ + k0 + scol),
          (__attribute__((address_space(3))) ushort_t*)(&sV[0][r0 * 64]),
          16, 0, 0);
    }
  }
  for (; kt < nkt; kt += KSPLIT) {
    const int k0 = kt * 64;
    __syncthreads();                           // buf[cur] staged & prior reads done
    if (kt + KSPLIT < nkt) {                   // async stage next chunk
      const int kn = (kt + KSPLIT) * 64;
#pragma unroll
      for (int j = 0; j < 2; j++) {
        const int r0 = w * 16 + j * 8;
        __builtin_amdgcn_global_load_lds(
            (const __attribute__((address_space(1))) ushort_t*)
                (kg + (size_t)(kn + r0 + srow) * HS + scol),
            (__attribute__((address_space(3))) ushort_t*)(&sK[cur ^ 1][r0 * 64]),
            16, 0, 0);
        __builtin_amdgcn_global_load_lds(
            (const __attribute__((address_space(1))) ushort_t*)
                (vg + (size_t)(r0 + srow) * TSEQ + kn + scol),
            (__attribute__((address_space(3))) ushort_t*)(&sV[cur ^ 1][r0 * 64]),
            16, 0, 0);
      }
    }
    const ushort_t* sKc = &sK[cur][0];
    const ushort_t* sVc = &sV[cur][0];
    const int sw = (l16 & 7) << 3;             // row-XOR (elems; 16B blocks)

    // ---- S^T = K Q^T : C[key = ct*16+quad*4+r][qrow = l16] ----
    f32x4 sT[4];
#pragma unroll
    for (int ct = 0; ct < 4; ct++) {
      sT[ct] = (f32x4){0.f, 0.f, 0.f, 0.f};
      const short8 kfa = *(const short8*)(sKc + (ct * 16 + l16) * 64 + ((quad * 8)      ^ sw));
      const short8 kfb = *(const short8*)(sKc + (ct * 16 + l16) * 64 + ((32 + quad * 8) ^ sw));
      sT[ct] = MFMA16(kfa, qf0, sT[ct]);
      sT[ct] = MFMA16(kfb, qf1, sT[ct]);
    }
    if (k0 + 63 > R0) {                        // causal mask, diagonal only
      const int qrow = R0 + l16;
#pragma unroll
      for (int ct = 0; ct < 4; ct++)
#pragma unroll
        for (int r = 0; r < 4; r++)
          sT[ct][r] = (k0 + ct * 16 + quad * 4 + r <= qrow) ? sT[ct][r] : -INFINITY;
    }
    // ---- online softmax (per-lane row; 2 cross-quad shuffles) ----
    float tm = -INFINITY;
#pragma unroll
    for (int ct = 0; ct < 4; ct++)
#pragma unroll
      for (int r = 0; r < 4; r++) tm = fmaxf(tm, sT[ct][r]);
    tm = fmaxf(tm, __shfl_xor(tm, 16));
    tm = fmaxf(tm, __shfl_xor(tm, 32));
    const float mn = fmaxf(mrow, tm);
    const float al = __expf(mrow - mn);
    mrow = mn;
    float ps = 0.f;
#pragma unroll
    for (int ct = 0; ct < 4; ct++)
#pragma unroll
      for (int r = 0; r < 4; r++) { sT[ct][r] = __expf(sT[ct][r] - mn); ps += sT[ct][r]; }
    ps += __shfl_xor(ps, 16);
    ps += __shfl_xor(ps, 32);
    lrow = lrow * al + ps;
    // ---- P -> LDS (A-layout), O rescale, PV ----
    ushort_t* Pw = &sP[w][0];
#pragma unroll
    for (int ct = 0; ct < 4; ct++) {
      ushort4 pk;
      pk.x = f2bf(sT[ct][0]); pk.y = f2bf(sT[ct][1]);
      pk.z = f2bf(sT[ct][2]); pk.w = f2bf(sT[ct][3]);
      *(ushort4*)(Pw + l16 * KP + ct * 16 + quad * 4) = pk;
    }
    float alo[4];
#pragma unroll
    for (int r = 0; r < 4; r++) alo[r] = __shfl(al, quad * 4 + r);
#pragma unroll
    for (int dt = 0; dt < 4; dt++)
#pragma unroll
      for (int r = 0; r < 4; r++) o[dt][r] *= alo[r];
    const short8 pf0 = *(const short8*)(Pw + l16 * KP +      quad * 8);
    const short8 pf1 = *(const short8*)(Pw + l16 * KP + 32 + quad * 8);
#pragma unroll
    for (int dt = 0; dt < 4; dt++) {
      const short8 vfa = *(const short8*)(sVc + (dt * 16 + l16) * 64 + ((quad * 8)      ^ sw));
      const short8 vfb = *(const short8*)(sVc + (dt * 16 + l16) * 64 + ((32 + quad * 8) ^ sw));
      o[dt] = MFMA16(pf0, vfa, o[dt]);
      o[dt] = MFMA16(pf1, vfb, o[dt]);
    }
    cur ^= 1;
  }

  // ---- write partials: ML fp32 [B][KSPLIT][T][2], OP bf16 [B][KSPLIT][T][64] ----
  const size_t base = ((size_t)(b * KSPLIT + s) * TSEQ);
  if (quad == 0) {
    ML[(base + R0 + l16) * 2 + 0] = mrow;
    ML[(base + R0 + l16) * 2 + 1] = lrow;
  }
#pragma unroll
  for (int dt = 0; dt < 4; dt++)
#pragma unroll
    for (int r = 0; r < 4; r++)
      OP[(base + R0 + quad * 4 + r) * HS + dt * 16 + l16] = f2bf(o[dt][r]);
}

// ---------------- attention pass 2: merge the KSPLIT partials ----------------
// grid 1024 x 256: block = 16 rows x 16 dim-groups.
__global__ __launch_bounds__(256) void attn_merge(
    const float* __restrict__ ML, const ushort_t* __restrict__ OP,
    float* __restrict__ out)
{
  const int row = blockIdx.x * 16 + (threadIdx.x >> 4);   // 0..16383
  const int b   = row >> 12, t = row & (TSEQ - 1);
  const int d0  = (threadIdx.x & 15) * 4;
  float m[KSPLIT], l[KSPLIT];
  float M = -INFINITY;
#pragma unroll
  for (int ss = 0; ss < KSPLIT; ss++) {
    const size_t i = ((size_t)(b * KSPLIT + ss) * TSEQ + t);
    m[ss] = ML[i * 2]; l[ss] = ML[i * 2 + 1];
    M = fmaxf(M, m[ss]);
  }
  float den = 0.f;
  float4 num = make_float4(0.f, 0.f, 0.f, 0.f);
#pragma unroll
  for (int ss = 0; ss < KSPLIT; ss++) {
    const float a = __expf(m[ss] - M);          // zero-trip split: weight 0
    den += l[ss] * a;
    const size_t i = ((size_t)(b * KSPLIT + ss) * TSEQ + t);
    const ushort4 u = *(const ushort4*)(OP + i * HS + d0);
    num.x += a * bf2f(u.x); num.y += a * bf2f(u.y);
    num.z += a * bf2f(u.z); num.w += a * bf2f(u.w);
  }
  const float inv = 1.f / den;
  *(float4*)(out + (size_t)row * HS + d0) =
      make_float4(num.x * inv, num.y * inv, num.z * inv, num.w * inv);
}

extern "C" void kernel_launch(void* const* d_in, const int* in_sizes, int n_in,
                              void* d_out, int out_size, void* d_ws, size_t ws_size,
                              hipStream_t stream) {
  const float* x  = (const float*)d_in[0];
  const float* Wq = (const float*)d_in[1];
  const float* Wk = (const float*)d_in[2];
  const float* Wv = (const float*)d_in[3];
  float* out = (float*)d_out;

  // ws: Wt 288K | q 2M | k 2M | vT 2M | ML 512K | OP 8M   (total ~15 MB)
  char* ws = (char*)d_ws;
  ushort_t* Wt = (ushort_t*)ws;
  ushort_t* qb = (ushort_t*)(ws + 294912);
  ushort_t* kb = (ushort_t*)(ws + 294912 + 2097152);
  ushort_t* vb = (ushort_t*)(ws + 294912 + 2 * 2097152);
  float*    ml = (float*)   (ws + 294912 + 3 * 2097152);
  ushort_t* op = (ushort_t*)(ws + 294912 + 3 * 2097152 + 524288);

  wprep<<<36, 256, 0, stream>>>(Wq, Wk, Wv, Wt);
  qkv_mfma<<<(NBATCH * TSEQ) / 32, 256, 0, stream>>>(x, Wt, qb, kb, vb);
  attn_part<<<64 * NBATCH * KSPLIT, 256, 0, stream>>>(qb, kb, vb, ml, op);
  attn_merge<<<1024, 256, 0, stream>>>(ml, op, out);
}